// Round 4
// baseline (110.259 us; speedup 1.0000x reference)
//
#include <hip/hip_runtime.h>

#define D_K 576
#define NSLAB 18         // 576 / 32
#define LBDA_INV 2.0f    // 1/lbda, lbda=0.5
#define HALF_LBDA 0.5f
#define EPS 0.01f
#define DSTRIDE 136      // Ds row stride (ushorts): 128 + 8 pad
#define DT_STRIDE 72     // DsT row stride (ushorts): 64 + 8 pad
#define POOL_USHORTS 17920  // max(staging 12288, Ds 8704 + DsT 9216)

typedef __attribute__((ext_vector_type(8))) short short8;
typedef __attribute__((ext_vector_type(4))) short short4v;
typedef __attribute__((ext_vector_type(4))) float f32x4;

__device__ inline short f2bf(float f) {
    unsigned u = __float_as_uint(f);
    u += 0x7FFF + ((u >> 16) & 1);   // round-to-nearest-even
    return (short)(u >> 16);
}
__device__ inline float bf2f(unsigned short s) {
    return __uint_as_float(((unsigned)s) << 16);
}

// ---------------- soft-min helpers (lbda = 0.5) ----------------
__device__ inline float softmin3(float a, float b, float c) {
    float mn = fminf(a, fminf(b, c));
    float s = __expf(-LBDA_INV * (a - mn)) + __expf(-LBDA_INV * (b - mn)) +
              __expf(-LBDA_INV * (c - mn));
    return mn - HALF_LBDA * __logf(s);
}
__device__ inline float softmin2(float a, float b) {
    float mn = fminf(a, b);
    float s = __expf(-LBDA_INV * (a - mn)) + __expf(-LBDA_INV * (b - mn));
    return mn - HALF_LBDA * __logf(s);
}

// OTAM DP over an 8x8 bf16 tile stored row-major in LDS with compile-time
// stride; rows streamed (8 live floats) to keep DP register footprint ~30.
template <int STRIDE>
__device__ float otam_dp_rows(const unsigned short* base) {
    float x[8], prev[10], cur[10];
    auto load_row = [&](int l) {
        short8 v = *(const short8*)(base + l * STRIDE);
#pragma unroll
        for (int j = 0; j < 8; ++j) x[j] = bf2f((unsigned short)v[j]);
    };
    load_row(0);
    prev[0] = 0.f;
#pragma unroll
    for (int m = 1; m <= 8; ++m) prev[m] = prev[m - 1] + x[m - 1];
    prev[9] = prev[8];  // pad col, d=0
#pragma unroll
    for (int l = 1; l < 8; ++l) {
        load_row(l);
        cur[0] = 0.f;
        cur[1] = x[0] + softmin3(prev[0], 0.f, prev[1]);
#pragma unroll
        for (int m = 2; m <= 8; ++m)
            cur[m] = x[m - 1] + softmin2(prev[m - 1], cur[m - 1]);
        cur[9] = softmin3(prev[8], cur[8], prev[9]);
#pragma unroll
        for (int m = 0; m < 10; ++m) prev[m] = cur[m];
    }
    return prev[9];
}

// ---------------- single fused kernel, 64x128 tiles, 4 blocks/CU ----------------
// Per block: 64 q-frame-rows x 128 s-frame-rows. Rolled K-loop (9 iters x 2 slabs),
// statically named double buffers in a union'd LDS pool, ONE staging register set.
// Per slab: issue next-slab f32 loads -> ds_read frags + 8 MFMA -> convert+ds_write
// -> barrier. Norms inline. Epilogue stores dist tile to Ds AND DsT so both DP
// directions run row-major; waves 0-1 do forward DP, waves 2-3 transposed DP.
__global__ __launch_bounds__(256, 4) void fused_kernel(
        const float* __restrict__ sup, const float* __restrict__ qry,
        float* __restrict__ out) {
    __shared__ __align__(16) unsigned short pool[POOL_USHORTS];  // 35.8 KB union
    __shared__ float qn_l[64], sn_l[128];
    unsigned short* const As0 = pool;            // 2048 ushorts (64x32 bf16)
    unsigned short* const Bs0 = pool + 2048;     // 4096 ushorts (128x32)
    unsigned short* const As1 = pool + 6144;     // 2048
    unsigned short* const Bs1 = pool + 8192;     // 4096
    unsigned short* const Ds  = pool;            // 64 x DSTRIDE  (8704)
    unsigned short* const DsT = pool + 8704;     // 128 x DT_STRIDE (9216)

    const int t = threadIdx.x;
    // XCD swizzle: the 4 blocks sharing a q-half-tile land on the same XCD
    const int b = blockIdx.x;
    const int xcd = b & 7, s2 = b >> 3;
    const int sblk = s2 >> 5;                 // 0..3
    const int qh = xcd * 32 + (s2 & 31);      // 0..255 (64-row q half-tiles)

    const float* qsrc = qry + (size_t)qh * 64 * D_K;
    const float* ssrc = sup + (size_t)sblk * 128 * D_K;

    // staging decomposition: thread t -> rows {j*32 + rr}, float4-col cc
    const int rr = t >> 3;        // 0..31
    const int cc = t & 7;         // 0..7
    const int c_in = cc >> 1, half = cc & 1;

    const int lane = t & 63;
    const int wave = t >> 6;
    const int wm = wave >> 1, wn = wave & 1;   // wave tile: 32 rows x 64 cols
    const int col16 = lane & 15, quad = lane >> 4;

    f32x4 acc[2][4];
#pragma unroll
    for (int i = 0; i < 2; ++i)
#pragma unroll
        for (int j = 0; j < 4; ++j) acc[i][j] = (f32x4){0.f, 0.f, 0.f, 0.f};

    // fragment read offsets + staging write offsets (XOR-swizzled rows)
    int aoff[2], boff[4], woffA[2], woffB[4];
#pragma unroll
    for (int mt = 0; mt < 2; ++mt) {
        int m = wm * 32 + mt * 16 + col16;     // 0..63
        aoff[mt] = (quad * 64 + (m ^ (quad << 1))) * 8;
    }
#pragma unroll
    for (int nt = 0; nt < 4; ++nt) {
        int n = wn * 64 + nt * 16 + col16;     // 0..127
        boff[nt] = (quad * 128 + (n ^ (quad << 1))) * 8;
    }
#pragma unroll
    for (int j = 0; j < 2; ++j)
        woffA[j] = (c_in * 64 + ((j * 32 + rr) ^ (c_in << 1))) * 8 + half * 4;
#pragma unroll
    for (int j = 0; j < 4; ++j)
        woffB[j] = (c_in * 128 + ((j * 32 + rr) ^ (c_in << 1))) * 8 + half * 4;

    float ssA[2] = {0.f, 0.f}, ssB[4] = {0.f, 0.f, 0.f, 0.f};
    float4 va[2], vb[4];

    auto stage_load = [&](int sl) {
        const int off = sl * 32 + cc * 4;
#pragma unroll
        for (int j = 0; j < 2; ++j)
            va[j] = *(const float4*)(qsrc + (size_t)(j * 32 + rr) * D_K + off);
#pragma unroll
        for (int j = 0; j < 4; ++j)
            vb[j] = *(const float4*)(ssrc + (size_t)(j * 32 + rr) * D_K + off);
    };
    auto stage_write = [&](unsigned short* __restrict__ A,
                           unsigned short* __restrict__ B) {
#pragma unroll
        for (int j = 0; j < 2; ++j) {
            ssA[j] += va[j].x * va[j].x + va[j].y * va[j].y +
                      va[j].z * va[j].z + va[j].w * va[j].w;
            short4v oa = {f2bf(va[j].x), f2bf(va[j].y), f2bf(va[j].z), f2bf(va[j].w)};
            *(short4v*)(&A[woffA[j]]) = oa;
        }
#pragma unroll
        for (int j = 0; j < 4; ++j) {
            ssB[j] += vb[j].x * vb[j].x + vb[j].y * vb[j].y +
                      vb[j].z * vb[j].z + vb[j].w * vb[j].w;
            short4v ob = {f2bf(vb[j].x), f2bf(vb[j].y), f2bf(vb[j].z), f2bf(vb[j].w)};
            *(short4v*)(&B[woffB[j]]) = ob;
        }
    };
    auto compute = [&](const unsigned short* __restrict__ A,
                       const unsigned short* __restrict__ B) {
        short8 af[2], bq[4];
#pragma unroll
        for (int mt = 0; mt < 2; ++mt) af[mt] = *(const short8*)(&A[aoff[mt]]);
#pragma unroll
        for (int nt = 0; nt < 4; ++nt) bq[nt] = *(const short8*)(&B[boff[nt]]);
#pragma unroll
        for (int mt = 0; mt < 2; ++mt)
#pragma unroll
            for (int nt = 0; nt < 4; ++nt)
                acc[mt][nt] = __builtin_amdgcn_mfma_f32_16x16x32_bf16(
                    af[mt], bq[nt], acc[mt][nt], 0, 0, 0);
    };

    // ---- prologue: stage slab 0 into buffer 0 ----
    stage_load(0);
    stage_write(As0, Bs0);
    __syncthreads();

    // ---- K loop: 9 iterations x 2 slabs, one barrier per slab ----
#pragma unroll 1
    for (int sp = 0; sp < 9; ++sp) {
        stage_load(2 * sp + 1);          // issue early (T14)
        compute(As0, Bs0);               // slab 2sp
        stage_write(As1, Bs1);           // convert + ds_write late
        __syncthreads();
        if (sp < 8) stage_load(2 * sp + 2);
        compute(As1, Bs1);               // slab 2sp+1
        if (sp < 8) stage_write(As0, Bs0);
        __syncthreads();
    }

    // ---- norms: octet shfl-reduce the per-thread partials ----
#pragma unroll
    for (int j = 0; j < 2; ++j) {
        float a = ssA[j];
        a += __shfl_down(a, 4); a += __shfl_down(a, 2); a += __shfl_down(a, 1);
        if ((t & 7) == 0) qn_l[j * 32 + rr] = sqrtf(a);
    }
#pragma unroll
    for (int j = 0; j < 4; ++j) {
        float s = ssB[j];
        s += __shfl_down(s, 4); s += __shfl_down(s, 2); s += __shfl_down(s, 1);
        if ((t & 7) == 0) sn_l[j * 32 + rr] = sqrtf(s);
    }
    __syncthreads();

    // ---- epilogue: dist -> Ds (row-major) AND DsT (transposed) as bf16 ----
    // C/D layout: col = lane&15, row = quad*4 + reg
#pragma unroll
    for (int mt = 0; mt < 2; ++mt) {
#pragma unroll
        for (int reg = 0; reg < 4; ++reg) {
            int m = wm * 32 + mt * 16 + quad * 4 + reg;
            float qv = qn_l[m];
#pragma unroll
            for (int nt = 0; nt < 4; ++nt) {
                int n = wn * 64 + nt * 16 + col16;
                float sv = sn_l[n];
                float dist = 1.f - acc[mt][nt][reg] * __builtin_amdgcn_rcpf(qv * sv + EPS);
                unsigned short h = (unsigned short)f2bf(dist);
                Ds[m * DSTRIDE + n] = h;
                DsT[n * DT_STRIDE + m] = h;
            }
        }
    }
    __syncthreads();

    // ---- DP phase: 128 (ql,sj) pairs; waves 0-1 forward, waves 2-3 transposed ----
    const int p = t & 127, ql = p >> 4, sj = p & 15;
    float r;
    if (t < 128) {
        r = otam_dp_rows<DSTRIDE>(Ds + (ql * 8) * DSTRIDE + sj * 8);      // dists
    } else {
        r = otam_dp_rows<DT_STRIDE>(DsT + (sj * 8) * DT_STRIDE + ql * 8); // dists^T
        sn_l[p] = r;
    }
    __syncthreads();
    if (t < 128) {
        int qg = qh * 8 + ql, sg = sblk * 16 + sj;
        out[qg * 64 + sg] = -(r + sn_l[p]);
    }
}

extern "C" void kernel_launch(void* const* d_in, const int* in_sizes, int n_in,
                              void* d_out, int out_size, void* d_ws, size_t ws_size,
                              hipStream_t stream) {
    const float* sup = (const float*)d_in[0];   // [64, 8, 576] -> 512 frame-rows
    const float* qry = (const float*)d_in[1];   // [2048, 8, 576] -> 16384 frame-rows
    float* out = (float*)d_out;                 // [2048, 64]
    (void)d_ws; (void)ws_size;                  // workspace unused (avoids poison fill)
    fused_kernel<<<dim3(1024), dim3(256), 0, stream>>>(sup, qry, out);
}

// Round 6
// 105.592 us; speedup vs baseline: 1.0442x; 1.0442x over previous
//
#include <hip/hip_runtime.h>

#define D_K 576
#define NSLAB 18         // 576 / 32
#define LBDA_INV 2.0f    // 1/lbda, lbda=0.5
#define HALF_LBDA 0.5f
#define EPS 0.01f
#define DSTRIDE 136      // Ds row stride (ushorts): 128 + 8 pad
#define DT_STRIDE 72     // DsT row stride (ushorts): 64 + 8 pad
#define POOL_USHORTS 17920  // max(staging 12288, Ds 8704 + DsT 9216)

typedef __attribute__((ext_vector_type(8))) short short8;
typedef __attribute__((ext_vector_type(4))) float f32x4;

// packed f32x2 -> bf16x2 (RNE), single VALU op on gfx950
__device__ inline unsigned cvt_pk_bf16(float lo, float hi) {
    unsigned r;
    asm("v_cvt_pk_bf16_f32 %0, %1, %2" : "=v"(r) : "v"(lo), "v"(hi));
    return r;
}

// ---------------- soft-min helpers (lbda = 0.5) ----------------
// softmin over {a,b} = mn - 0.5*ln(1 + e^{-2(mx-mn)})  (one exp, not two)
__device__ inline float softmin2(float a, float b) {
    float mn = fminf(a, b), mx = fmaxf(a, b);
    return mn - HALF_LBDA * __logf(1.f + __expf(LBDA_INV * (mn - mx)));
}
// softmin over {a,b,c}: sort via min3/med3/max3, drop the exp(0)=1 term
__device__ inline float softmin3(float a, float b, float c) {
    float mn = fminf(fminf(a, b), c);
    float mx = fmaxf(fmaxf(a, b), c);
    float md = __builtin_amdgcn_fmed3f(a, b, c);
    float s = 1.f + __expf(LBDA_INV * (mn - md)) + __expf(LBDA_INV * (mn - mx));
    return mn - HALF_LBDA * __logf(s);
}

// OTAM DP over an 8x8 bf16 tile stored row-major in LDS with compile-time
// stride; rows streamed. bf16 pairs unpacked with shift/mask (1 op/elem).
template <int STRIDE>
__device__ float otam_dp_rows(const unsigned short* base) {
    float x[8], prev[10], cur[10];
    auto load_row = [&](int l) {
        uint4 v = *(const uint4*)(base + l * STRIDE);
        x[0] = __uint_as_float(v.x << 16);
        x[1] = __uint_as_float(v.x & 0xFFFF0000u);
        x[2] = __uint_as_float(v.y << 16);
        x[3] = __uint_as_float(v.y & 0xFFFF0000u);
        x[4] = __uint_as_float(v.z << 16);
        x[5] = __uint_as_float(v.z & 0xFFFF0000u);
        x[6] = __uint_as_float(v.w << 16);
        x[7] = __uint_as_float(v.w & 0xFFFF0000u);
    };
    load_row(0);
    prev[0] = 0.f;
#pragma unroll
    for (int m = 1; m <= 8; ++m) prev[m] = prev[m - 1] + x[m - 1];
    prev[9] = prev[8];  // pad col, d=0
#pragma unroll
    for (int l = 1; l < 8; ++l) {
        load_row(l);
        cur[0] = 0.f;
        cur[1] = x[0] + softmin3(prev[0], 0.f, prev[1]);
#pragma unroll
        for (int m = 2; m <= 8; ++m)
            cur[m] = x[m - 1] + softmin2(prev[m - 1], cur[m - 1]);
        cur[9] = softmin3(prev[8], cur[8], prev[9]);
#pragma unroll
        for (int m = 0; m < 10; ++m) prev[m] = cur[m];
    }
    return prev[9];
}

// ---------------- single fused kernel, 64x128 tiles, 4 blocks/CU ----------------
// Structure identical to round 4 (rolled 9x2 K-loop, named double buffers, T14
// load-early/write-late, union'd LDS pool, dual-direction DP). This round only
// cuts VALU instruction count: cvt_pk staging/epilogue, 1-exp softmins, packed
// DsT writes, shift/mask DP unpack.
__global__ __launch_bounds__(256, 4) void fused_kernel(
        const float* __restrict__ sup, const float* __restrict__ qry,
        float* __restrict__ out) {
    __shared__ __align__(16) unsigned short pool[POOL_USHORTS];  // 35.8 KB union
    __shared__ float qn_l[64], sn_l[128];
    unsigned short* const As0 = pool;            // 2048 ushorts (64x32 bf16)
    unsigned short* const Bs0 = pool + 2048;     // 4096 ushorts (128x32)
    unsigned short* const As1 = pool + 6144;     // 2048
    unsigned short* const Bs1 = pool + 8192;     // 4096
    unsigned short* const Ds  = pool;            // 64 x DSTRIDE  (8704)
    unsigned short* const DsT = pool + 8704;     // 128 x DT_STRIDE (9216)

    const int t = threadIdx.x;
    // XCD swizzle: the 4 blocks sharing a q-half-tile land on the same XCD
    const int b = blockIdx.x;
    const int xcd = b & 7, s2 = b >> 3;
    const int sblk = s2 >> 5;                 // 0..3
    const int qh = xcd * 32 + (s2 & 31);      // 0..255 (64-row q half-tiles)

    const float* qsrc = qry + (size_t)qh * 64 * D_K;
    const float* ssrc = sup + (size_t)sblk * 128 * D_K;

    // staging decomposition: thread t -> rows {j*32 + rr}, float4-col cc
    const int rr = t >> 3;        // 0..31
    const int cc = t & 7;         // 0..7
    const int c_in = cc >> 1, half = cc & 1;

    const int lane = t & 63;
    const int wave = t >> 6;
    const int wm = wave >> 1, wn = wave & 1;   // wave tile: 32 rows x 64 cols
    const int col16 = lane & 15, quad = lane >> 4;

    f32x4 acc[2][4];
#pragma unroll
    for (int i = 0; i < 2; ++i)
#pragma unroll
        for (int j = 0; j < 4; ++j) acc[i][j] = (f32x4){0.f, 0.f, 0.f, 0.f};

    // fragment read offsets + staging write offsets (XOR-swizzled rows)
    int aoff[2], boff[4], woffA[2], woffB[4];
#pragma unroll
    for (int mt = 0; mt < 2; ++mt) {
        int m = wm * 32 + mt * 16 + col16;     // 0..63
        aoff[mt] = (quad * 64 + (m ^ (quad << 1))) * 8;
    }
#pragma unroll
    for (int nt = 0; nt < 4; ++nt) {
        int n = wn * 64 + nt * 16 + col16;     // 0..127
        boff[nt] = (quad * 128 + (n ^ (quad << 1))) * 8;
    }
#pragma unroll
    for (int j = 0; j < 2; ++j)
        woffA[j] = (c_in * 64 + ((j * 32 + rr) ^ (c_in << 1))) * 8 + half * 4;
#pragma unroll
    for (int j = 0; j < 4; ++j)
        woffB[j] = (c_in * 128 + ((j * 32 + rr) ^ (c_in << 1))) * 8 + half * 4;

    float ssA[2] = {0.f, 0.f}, ssB[4] = {0.f, 0.f, 0.f, 0.f};
    float4 va[2], vb[4];

    auto stage_load = [&](int sl) {
        const int off = sl * 32 + cc * 4;
#pragma unroll
        for (int j = 0; j < 2; ++j)
            va[j] = *(const float4*)(qsrc + (size_t)(j * 32 + rr) * D_K + off);
#pragma unroll
        for (int j = 0; j < 4; ++j)
            vb[j] = *(const float4*)(ssrc + (size_t)(j * 32 + rr) * D_K + off);
    };
    auto stage_write = [&](unsigned short* __restrict__ A,
                           unsigned short* __restrict__ B) {
#pragma unroll
        for (int j = 0; j < 2; ++j) {
            ssA[j] += va[j].x * va[j].x + va[j].y * va[j].y +
                      va[j].z * va[j].z + va[j].w * va[j].w;
            uint2 u;
            u.x = cvt_pk_bf16(va[j].x, va[j].y);
            u.y = cvt_pk_bf16(va[j].z, va[j].w);
            *(uint2*)(&A[woffA[j]]) = u;
        }
#pragma unroll
        for (int j = 0; j < 4; ++j) {
            ssB[j] += vb[j].x * vb[j].x + vb[j].y * vb[j].y +
                      vb[j].z * vb[j].z + vb[j].w * vb[j].w;
            uint2 u;
            u.x = cvt_pk_bf16(vb[j].x, vb[j].y);
            u.y = cvt_pk_bf16(vb[j].z, vb[j].w);
            *(uint2*)(&B[woffB[j]]) = u;
        }
    };
    auto compute = [&](const unsigned short* __restrict__ A,
                       const unsigned short* __restrict__ B) {
        short8 af[2], bq[4];
#pragma unroll
        for (int mt = 0; mt < 2; ++mt) af[mt] = *(const short8*)(&A[aoff[mt]]);
#pragma unroll
        for (int nt = 0; nt < 4; ++nt) bq[nt] = *(const short8*)(&B[boff[nt]]);
#pragma unroll
        for (int mt = 0; mt < 2; ++mt)
#pragma unroll
            for (int nt = 0; nt < 4; ++nt)
                acc[mt][nt] = __builtin_amdgcn_mfma_f32_16x16x32_bf16(
                    af[mt], bq[nt], acc[mt][nt], 0, 0, 0);
    };

    // ---- prologue: stage slab 0 into buffer 0 ----
    stage_load(0);
    stage_write(As0, Bs0);
    __syncthreads();

    // ---- K loop: 9 iterations x 2 slabs, one barrier per slab ----
#pragma unroll 1
    for (int sp = 0; sp < 9; ++sp) {
        stage_load(2 * sp + 1);          // issue early (T14)
        compute(As0, Bs0);               // slab 2sp
        stage_write(As1, Bs1);           // convert + ds_write late
        __syncthreads();
        if (sp < 8) stage_load(2 * sp + 2);
        compute(As1, Bs1);               // slab 2sp+1
        if (sp < 8) stage_write(As0, Bs0);
        __syncthreads();
    }

    // ---- norms: octet shfl-reduce the per-thread partials ----
#pragma unroll
    for (int j = 0; j < 2; ++j) {
        float a = ssA[j];
        a += __shfl_down(a, 4); a += __shfl_down(a, 2); a += __shfl_down(a, 1);
        if ((t & 7) == 0) qn_l[j * 32 + rr] = sqrtf(a);
    }
#pragma unroll
    for (int j = 0; j < 4; ++j) {
        float s = ssB[j];
        s += __shfl_down(s, 4); s += __shfl_down(s, 2); s += __shfl_down(s, 1);
        if ((t & 7) == 0) sn_l[j * 32 + rr] = sqrtf(s);
    }
    __syncthreads();

    // ---- epilogue: dist -> Ds (scalar b16) AND DsT (packed b64) as bf16 ----
    // C/D layout: col = lane&15, row = quad*4 + reg
#pragma unroll
    for (int mt = 0; mt < 2; ++mt) {
        const int m = wm * 32 + mt * 16 + quad * 4;
        float q0 = qn_l[m], q1 = qn_l[m + 1], q2 = qn_l[m + 2], q3 = qn_l[m + 3];
#pragma unroll
        for (int nt = 0; nt < 4; ++nt) {
            const int n = wn * 64 + nt * 16 + col16;
            float sv = sn_l[n];
            float d0 = 1.f - acc[mt][nt][0] * __builtin_amdgcn_rcpf(q0 * sv + EPS);
            float d1 = 1.f - acc[mt][nt][1] * __builtin_amdgcn_rcpf(q1 * sv + EPS);
            float d2 = 1.f - acc[mt][nt][2] * __builtin_amdgcn_rcpf(q2 * sv + EPS);
            float d3 = 1.f - acc[mt][nt][3] * __builtin_amdgcn_rcpf(q3 * sv + EPS);
            uint2 u;
            u.x = cvt_pk_bf16(d0, d1);
            u.y = cvt_pk_bf16(d2, d3);
            *(uint2*)(&DsT[n * DT_STRIDE + m]) = u;     // row n, cols m..m+3
            Ds[(m + 0) * DSTRIDE + n] = (unsigned short)(u.x);
            Ds[(m + 1) * DSTRIDE + n] = (unsigned short)(u.x >> 16);
            Ds[(m + 2) * DSTRIDE + n] = (unsigned short)(u.y);
            Ds[(m + 3) * DSTRIDE + n] = (unsigned short)(u.y >> 16);
        }
    }
    __syncthreads();

    // ---- DP phase: 128 (ql,sj) pairs; waves 0-1 forward, waves 2-3 transposed ----
    const int p = t & 127, ql = p >> 4, sj = p & 15;
    float r;
    if (t < 128) {
        r = otam_dp_rows<DSTRIDE>(Ds + (ql * 8) * DSTRIDE + sj * 8);      // dists
    } else {
        r = otam_dp_rows<DT_STRIDE>(DsT + (sj * 8) * DT_STRIDE + ql * 8); // dists^T
        sn_l[p] = r;
    }
    __syncthreads();
    if (t < 128) {
        int qg = qh * 8 + ql, sg = sblk * 16 + sj;
        out[qg * 64 + sg] = -(r + sn_l[p]);
    }
}

extern "C" void kernel_launch(void* const* d_in, const int* in_sizes, int n_in,
                              void* d_out, int out_size, void* d_ws, size_t ws_size,
                              hipStream_t stream) {
    const float* sup = (const float*)d_in[0];   // [64, 8, 576] -> 512 frame-rows
    const float* qry = (const float*)d_in[1];   // [2048, 8, 576] -> 16384 frame-rows
    float* out = (float*)d_out;                 // [2048, 64]
    (void)d_ws; (void)ws_size;                  // workspace unused
    fused_kernel<<<dim3(1024), dim3(256), 0, stream>>>(sup, qry, out);
}